// Round 7
// baseline (63.772 us; speedup 1.0000x reference)
//
#include <hip/hip_runtime.h>
#include <hip/hip_bf16.h>
#include <math.h>

// ImplicitPolygonInjector: B=4, C=128, H=W=64, S=4
// out[b][j][h*4+sy][w*4+sx] = (relu(hf[b,h,w,:]+hg[sy,sx,:]+b1) @ w2 + b2)[j] * gate[b,h,w]
//
// R6: occupancy push. Blocks of 8 w (grid 2048), LDS ~19.4KB, hf stored bf16,
// launch_bounds(256,5) -> 5 blocks/CU resident (20 waves) + 8 blocks/CU of work.
// Steady state identical to R3 (best measured): per sy-quarter {A; bar; B+stores; bar},
// lgkm-only barriers, no global loads after prologue -> stores never drained.

typedef __attribute__((ext_vector_type(8))) short bf16x8;
typedef __attribute__((ext_vector_type(4))) float f32x4;

__device__ inline short f2bf(float v) {
    __hip_bfloat16 b = __float2bfloat16(v);
    return *reinterpret_cast<short*>(&b);
}
__device__ inline float bf2f(short s) {
    __hip_bfloat16 b = *reinterpret_cast<__hip_bfloat16*>(&s);
    return __bfloat162float(b);
}

__device__ inline void barrier_lgkm() {
    asm volatile("s_waitcnt lgkmcnt(0)" ::: "memory");
    __builtin_amdgcn_s_barrier();
    asm volatile("" ::: "memory");
}

// ---------------- pre-kernel: transposes + bf16 hi/lo split ----------------
__global__ __launch_bounds__(256) void ipi_pre_kernel(
    const float* __restrict__ w2,    // (128,128)
    const float* __restrict__ w1,    // (130,128) -- rows 0..127 used
    const float* __restrict__ gw1,   // (128,32)
    __hip_bfloat16* __restrict__ w2t,     // (128j,128k)
    __hip_bfloat16* __restrict__ w1t_hi,  // (128j,128c)
    __hip_bfloat16* __restrict__ w1t_lo,
    __hip_bfloat16* __restrict__ g1t_hi,  // (32jg,128c)
    __hip_bfloat16* __restrict__ g1t_lo)
{
    int gid = blockIdx.x * 256 + threadIdx.x;
    if (gid < 16384) {
        int j = gid >> 7, k = gid & 127;
        w2t[gid] = __float2bfloat16(w2[k * 128 + j]);
    } else if (gid < 32768) {
        int i = gid - 16384, j = i >> 7, c = i & 127;
        float v = w1[c * 128 + j];
        __hip_bfloat16 hi = __float2bfloat16(v);
        w1t_hi[i] = hi;
        w1t_lo[i] = __float2bfloat16(v - __bfloat162float(hi));
    } else if (gid < 36864) {
        int i = gid - 32768, jg = i >> 7, c = i & 127;
        float v = gw1[c * 32 + jg];
        __hip_bfloat16 hi = __float2bfloat16(v);
        g1t_hi[i] = hi;
        g1t_lo[i] = __float2bfloat16(v - __bfloat162float(hi));
    }
}

// ---------------- main kernel ----------------
__global__ __launch_bounds__(256, 5) void ipi_main(
    const float* __restrict__ feat,     // (4,128,64,64)
    const float* __restrict__ mlp_w1,   // (130,128) -- rows 128,129 (grid coords)
    const float* __restrict__ mlp_b1,   // (128,)
    const float* __restrict__ gate_w2,  // (32,)
    const float* __restrict__ gate_b2,  // (1,)
    const float* __restrict__ mlp_b2,   // (128,)
    const __hip_bfloat16* __restrict__ w2t,
    const __hip_bfloat16* __restrict__ w1t_hi,
    const __hip_bfloat16* __restrict__ w1t_lo,
    const __hip_bfloat16* __restrict__ g1t_hi,
    const __hip_bfloat16* __restrict__ g1t_lo,
    float* __restrict__ out)            // (4,128,256,256)
{
    __shared__ short hf_s[8 * 136];     // hf[w][j] bf16 (stride 136 -> 16B-aligned rows)
    __shared__ float hgb_s[16 * 132];   // hgb[s][k] fp32
    __shared__ float gate_s[8];
    __shared__ float glds[8 * 33];      // gate hidden
    __shared__ char  hid[8192];         // [32 m][128 k] bf16, XOR-swizzled
    short* f_hi = (short*)hid;          // [8 w][136 c] (prologue only)
    short* f_lo = (short*)(hid + 2176);

    const int t    = threadIdx.x;
    const int lane = t & 63;
    const int lg   = lane >> 4;         // 0..3
    const int ml   = lane & 15;
    const int wv   = t >> 6;            // wave id -> j-range wv*32..+31
    const int bx   = blockIdx.x;
    const int w0   = (bx & 7) * 8;      // 8 w per block
    const int h    = (bx >> 3) & 63;
    const int b    = bx >> 9;

    // ---- w2t A-frags + b2 ----
    bf16x8 afrag[2][4];
    f32x4  b2v[2];
    {
        const __hip_bfloat16* base = w2t + (wv * 32 + ml) * 128 + lg * 8;
        #pragma unroll
        for (int jt = 0; jt < 2; ++jt) {
            #pragma unroll
            for (int ks = 0; ks < 4; ++ks)
                afrag[jt][ks] = *(const bf16x8*)(base + jt * 2048 + ks * 32);
            b2v[jt] = *(const f32x4*)&mlp_b2[wv * 32 + jt * 16 + lg * 4];
        }
    }

    // store base: column = w0*4 + mrow, plane j = wv*32 + jt*16 + lg*4 + r
    float* pb = out + ((size_t)(b * 128 + wv * 32 + lg * 4) << 16)
                    + (size_t)(h * 4) * 256 + w0 * 4 + ml;

    // ---- stage f (transposed, bf16 hi/lo) + hgb ----
    {
        const float* fbase = feat + ((size_t)(b * 128) * 64 + h) * 64 + w0;
        #pragma unroll
        for (int i = 0; i < 4; ++i) {
            int idx = t + i * 256;            // 1024 = 128c * 8w
            int c = idx >> 3, w = idx & 7;
            float v = fbase[(size_t)c * 4096 + w];
            short hi = f2bf(v);
            f_hi[w * 136 + c] = hi;
            f_lo[w * 136 + c] = f2bf(v - bf2f(hi));
        }
        #pragma unroll
        for (int i = 0; i < 8; ++i) {
            int idx = t + i * 256;            // 2048 = 16s * 128k
            int s = idx >> 7, k = idx & 127;
            float cx = -0.75f + 0.5f * (float)(s & 3);
            float cy = -0.75f + 0.5f * (float)(s >> 2);
            hgb_s[s * 132 + k] = cx * mlp_w1[16384 + k]
                               + cy * mlp_w1[16512 + k] + mlp_b1[k];
        }
    }
    barrier_lgkm();

    // ---- hf = f @ w1_f via split-bf16 MFMA (rows 8..15 zero); gate (wave 0) ----
    {
        bf16x8 fhi[4], flo[4];
        if (ml < 8) {
            const short* fb  = f_hi + ml * 136 + lg * 8;
            const short* flb = f_lo + ml * 136 + lg * 8;
            #pragma unroll
            for (int ks = 0; ks < 4; ++ks) {
                fhi[ks] = *(const bf16x8*)(fb + ks * 32);
                flo[ks] = *(const bf16x8*)(flb + ks * 32);
            }
        } else {
            #pragma unroll
            for (int ks = 0; ks < 4; ++ks) {
                fhi[ks] = (bf16x8)(short)0;
                flo[ks] = (bf16x8)(short)0;
            }
        }
        #pragma unroll
        for (int jj = 0; jj < 2; ++jj) {
            const int jt16 = (wv * 2 + jj) * 16;
            const __hip_bfloat16* bh = w1t_hi + (jt16 + ml) * 128 + lg * 8;
            const __hip_bfloat16* bl = w1t_lo + (jt16 + ml) * 128 + lg * 8;
            f32x4 acc = {0.f, 0.f, 0.f, 0.f};
            #pragma unroll
            for (int ks = 0; ks < 4; ++ks) {
                bf16x8 Bh = *(const bf16x8*)(bh + ks * 32);
                bf16x8 Bl = *(const bf16x8*)(bl + ks * 32);
                acc = __builtin_amdgcn_mfma_f32_16x16x32_bf16(fhi[ks], Bh, acc, 0, 0, 0);
                acc = __builtin_amdgcn_mfma_f32_16x16x32_bf16(fhi[ks], Bl, acc, 0, 0, 0);
                acc = __builtin_amdgcn_mfma_f32_16x16x32_bf16(flo[ks], Bh, acc, 0, 0, 0);
            }
            if (lg < 2) {                    // D rows 0..7 valid (= w)
                #pragma unroll
                for (int r = 0; r < 4; ++r)
                    hf_s[(lg * 4 + r) * 136 + jt16 + ml] = f2bf(acc[r]);
            }
        }
        if (wv == 0) {
            #pragma unroll
            for (int jt = 0; jt < 2; ++jt) {
                const __hip_bfloat16* bh = g1t_hi + (jt * 16 + ml) * 128 + lg * 8;
                const __hip_bfloat16* bl = g1t_lo + (jt * 16 + ml) * 128 + lg * 8;
                f32x4 acc = {0.f, 0.f, 0.f, 0.f};
                #pragma unroll
                for (int ks = 0; ks < 4; ++ks) {
                    bf16x8 Bh = *(const bf16x8*)(bh + ks * 32);
                    bf16x8 Bl = *(const bf16x8*)(bl + ks * 32);
                    acc = __builtin_amdgcn_mfma_f32_16x16x32_bf16(fhi[ks], Bh, acc, 0, 0, 0);
                    acc = __builtin_amdgcn_mfma_f32_16x16x32_bf16(fhi[ks], Bl, acc, 0, 0, 0);
                    acc = __builtin_amdgcn_mfma_f32_16x16x32_bf16(flo[ks], Bh, acc, 0, 0, 0);
                }
                if (lg < 2) {
                    #pragma unroll
                    for (int r = 0; r < 4; ++r) {
                        float v = acc[r];
                        glds[(lg * 4 + r) * 33 + jt * 16 + ml] = (v >= 0.f) ? v : 0.2f * v;
                    }
                }
            }
        }
    }
    barrier_lgkm();

    // ---- phase A: quarter q -> hid[32 m][128 k]; m = w*4+sx, rows mq = t>>3 ----
    const int mq  = t >> 3;             // 0..31
    const int kq  = t & 7;              // k16 chunk
    const int aw  = mq >> 2;            // w 0..7
    const int asw = (mq & 7) << 4;
    auto phaseA = [&](int q) {
        const short* hfr = hf_s + aw * 136 + kq * 16;
        const float* hgr = hgb_s + (q * 4 + (mq & 3)) * 132 + kq * 16;
        char* wp = hid + mq * 256;
        bf16x8 h0 = *(const bf16x8*)(hfr);
        float4 g0 = *(const float4*)(hgr);
        float4 g1 = *(const float4*)(hgr + 4);
        bf16x8 hv0;
        hv0[0] = f2bf(fmaxf(bf2f(h0[0]) + g0.x, 0.f));
        hv0[1] = f2bf(fmaxf(bf2f(h0[1]) + g0.y, 0.f));
        hv0[2] = f2bf(fmaxf(bf2f(h0[2]) + g0.z, 0.f));
        hv0[3] = f2bf(fmaxf(bf2f(h0[3]) + g0.w, 0.f));
        hv0[4] = f2bf(fmaxf(bf2f(h0[4]) + g1.x, 0.f));
        hv0[5] = f2bf(fmaxf(bf2f(h0[5]) + g1.y, 0.f));
        hv0[6] = f2bf(fmaxf(bf2f(h0[6]) + g1.z, 0.f));
        hv0[7] = f2bf(fmaxf(bf2f(h0[7]) + g1.w, 0.f));
        *(bf16x8*)(wp + ((kq * 32) ^ asw)) = hv0;
        bf16x8 h1 = *(const bf16x8*)(hfr + 8);
        float4 g2 = *(const float4*)(hgr + 8);
        float4 g3 = *(const float4*)(hgr + 12);
        bf16x8 hv1;
        hv1[0] = f2bf(fmaxf(bf2f(h1[0]) + g2.x, 0.f));
        hv1[1] = f2bf(fmaxf(bf2f(h1[1]) + g2.y, 0.f));
        hv1[2] = f2bf(fmaxf(bf2f(h1[2]) + g2.z, 0.f));
        hv1[3] = f2bf(fmaxf(bf2f(h1[3]) + g2.w, 0.f));
        hv1[4] = f2bf(fmaxf(bf2f(h1[4]) + g3.x, 0.f));
        hv1[5] = f2bf(fmaxf(bf2f(h1[5]) + g3.y, 0.f));
        hv1[6] = f2bf(fmaxf(bf2f(h1[6]) + g3.z, 0.f));
        hv1[7] = f2bf(fmaxf(bf2f(h1[7]) + g3.w, 0.f));
        *(bf16x8*)(wp + ((kq * 32 + 16) ^ asw)) = hv1;
    };

    // ---- interval: gate sigmoid || phase A(0) (glds is separate LDS now) ----
    if (t < 8) {
        float s = gate_b2[0];
        #pragma unroll 8
        for (int jg = 0; jg < 32; ++jg) s = fmaf(glds[t * 33 + jg], gate_w2[jg], s);
        gate_s[t] = 1.f / (1.f + expf(-s));
    }
    phaseA(0);
    barrier_lgkm();

    // ---- steady state: per quarter {B(q)+stores; bar; A(q+1); bar} ----
    #pragma unroll
    for (int q = 0; q < 4; ++q) {
        #pragma unroll
        for (int mt = 0; mt < 2; ++mt) {
            const int row = mt * 16 + ml;       // 0..31
            const int swb = (row & 7) << 4;
            const char* rp = hid + row * 256;
            bf16x8 bfrag[4];
            #pragma unroll
            for (int ks = 0; ks < 4; ++ks)
                bfrag[ks] = *(const bf16x8*)(rp + ((ks * 64 + lg * 16) ^ swb));

            f32x4 acc0 = b2v[0];
            f32x4 acc1 = b2v[1];
            #pragma unroll
            for (int ks = 0; ks < 4; ++ks) {
                acc0 = __builtin_amdgcn_mfma_f32_16x16x32_bf16(afrag[0][ks], bfrag[ks], acc0, 0, 0, 0);
                acc1 = __builtin_amdgcn_mfma_f32_16x16x32_bf16(afrag[1][ks], bfrag[ks], acc1, 0, 0, 0);
            }

            const float g = gate_s[row >> 2];
            float* op = pb + q * 256 + mt * 16;
            #pragma unroll
            for (int r = 0; r < 4; ++r) {
                op[(size_t)r << 16]        = acc0[r] * g;
                op[(size_t)(r + 16) << 16] = acc1[r] * g;
            }
        }
        barrier_lgkm();
        if (q < 3) {
            phaseA(q + 1);
            barrier_lgkm();
        }
    }
}

extern "C" void kernel_launch(void* const* d_in, const int* in_sizes, int n_in,
                              void* d_out, int out_size, void* d_ws, size_t ws_size,
                              hipStream_t stream) {
    const float* feat = (const float*)d_in[0];
    const float* gw1  = (const float*)d_in[1];
    const float* gw2  = (const float*)d_in[2];
    const float* gb2  = (const float*)d_in[3];
    const float* w1   = (const float*)d_in[4];
    const float* b1   = (const float*)d_in[5];
    const float* w2   = (const float*)d_in[6];
    const float* b2   = (const float*)d_in[7];
    float* o = (float*)d_out;

    // ws: w2t 32K | w1t_hi 32K | w1t_lo 32K | g1t_hi 8K | g1t_lo 8K = 112K
    char* ws = (char*)d_ws;
    __hip_bfloat16* w2t    = (__hip_bfloat16*)(ws);
    __hip_bfloat16* w1t_hi = (__hip_bfloat16*)(ws + 32768);
    __hip_bfloat16* w1t_lo = (__hip_bfloat16*)(ws + 65536);
    __hip_bfloat16* g1t_hi = (__hip_bfloat16*)(ws + 98304);
    __hip_bfloat16* g1t_lo = (__hip_bfloat16*)(ws + 106496);

    ipi_pre_kernel<<<dim3(144), dim3(256), 0, stream>>>(
        w2, w1, gw1, w2t, w1t_hi, w1t_lo, g1t_hi, g1t_lo);
    ipi_main<<<dim3(2048), dim3(256), 0, stream>>>(
        feat, w1, b1, gw2, gb2, b2, w2t, w1t_hi, w1t_lo, g1t_hi, g1t_lo, o);
}